// Round 1
// baseline (1903.650 us; speedup 1.0000x reference)
//
#include <hip/hip_runtime.h>
#include <hip/hip_bf16.h>
#include <cstdint>

// ---------------------------------------------------------------------------
// Decoder LSTM (teacher-forced), MI355X.
//   1. cvt_bf16: W_out, W_ih, W_hh fp32 -> bf16 (ws)
//   2. gather_embed: X[t*16+b] = bf16(relu(emb[tok])) (t-major), zero flags
//   3. gemm_bt: G0 = X @ W_ih^T + b_ih + b_hh  (fp32, t-major rows)
//   4. fused kernel, grid 256 (1 block/CU via 84KB LDS):
//      - blocks 0..15: lock-free recurrence. W_hh slice in REGISTERS,
//        h exchange via relaxed agent-scope (sc0/sc1 write-through) atomics,
//        per-block sum-barrier flags (separate cachelines), in-wave gate
//        exchange -> NO __syncthreads / threadfence in the 128-step loop.
//      - blocks 16..255: persistent GEMM workers computing logits tiles,
//        flag-gated per t-range; overlap the big GEMM under the recurrence.
// ---------------------------------------------------------------------------

#define V_ 32000
#define H_ 512
#define B_ 16
#define T_ 128

typedef __attribute__((ext_vector_type(8))) short s16x8;
typedef __attribute__((ext_vector_type(4))) float f32x4;

typedef unsigned int __attribute__((address_space(1))) as1_u32;
typedef unsigned int __attribute__((address_space(3))) as3_u32;

#define MFMA16 __builtin_amdgcn_mfma_f32_16x16x32_bf16

__device__ __forceinline__ void async_cp16(const void* g, void* l) {
  __builtin_amdgcn_global_load_lds((const as1_u32*)g, (as3_u32*)l, 16, 0, 0);
}

__device__ __forceinline__ short f2bf(float f) {
  union { float f; unsigned u; } v; v.f = f;
  unsigned r = v.u + 0x7fffu + ((v.u >> 16) & 1u);   // RNE, inputs finite
  return (short)(r >> 16);
}

// 16B coherent (device-scope) load: two relaxed agent atomic 64-bit loads.
// Compiler emits sc0/sc1 loads that bypass stale L1/L2 -> always IF-current.
__device__ __forceinline__ s16x8 load_h16(const short* p) {
  unsigned long long* q = (unsigned long long*)(void*)p;
  unsigned long long lo = __hip_atomic_load(q, __ATOMIC_RELAXED, __HIP_MEMORY_SCOPE_AGENT);
  unsigned long long hi = __hip_atomic_load(q + 1, __ATOMIC_RELAXED, __HIP_MEMORY_SCOPE_AGENT);
  union { unsigned long long u[2]; s16x8 v; } r;
  r.u[0] = lo; r.u[1] = hi;
  return r.v;
}

// ---------------------------------------------------------------------------
__global__ void cvt_bf16(const float* __restrict__ in, short* __restrict__ out, int n4) {
  int i = blockIdx.x * blockDim.x + threadIdx.x;
  if (i >= n4) return;
  float4 v = ((const float4*)in)[i];
  short4 o;
  o.x = f2bf(v.x); o.y = f2bf(v.y); o.z = f2bf(v.z); o.w = f2bf(v.w);
  ((short4*)out)[i] = o;
}

// grid 2048 blocks (one per (b,t)), 128 threads. X stored T-MAJOR: row t*16+b.
__global__ void gather_embed(const float* __restrict__ emb, const int* __restrict__ tgt,
                             short* __restrict__ X, int* __restrict__ flags) {
  int m = blockIdx.x;
  int b = m >> 7, t = m & 127;
  int tok = (t == 0) ? 1 : tgt[b * T_ + t - 1];       // BOS = 1
  int k = threadIdx.x * 4;
  float4 v = *(const float4*)&emb[(size_t)tok * H_ + k];
  short4 o;
  o.x = f2bf(fmaxf(v.x, 0.f)); o.y = f2bf(fmaxf(v.y, 0.f));
  o.z = f2bf(fmaxf(v.z, 0.f)); o.w = f2bf(fmaxf(v.w, 0.f));
  *(short4*)&X[((size_t)t * 16 + b) * H_ + k] = o;
  if (m == 0) {                                       // zero 256 flag ints
    flags[threadIdx.x] = 0;
    flags[128 + threadIdx.x] = 0;
  }
}

// ---------------------------------------------------------------------------
// C = A(MxK bf16) @ B(NxK bf16)^T + bias ; 128x128 tile, BK=64, 4 waves,
// XOR-swizzled LDS chunks. Used for G0 = X @ W_ih^T.
__global__ __launch_bounds__(256, 2) void gemm_bt(
    const short* __restrict__ A, const short* __restrict__ B,
    const float* __restrict__ bias0, const float* __restrict__ bias1,
    float* __restrict__ out, int M, int N, int K, int ldo)
{
  __shared__ short As[1024 * 8];
  __shared__ short Bs[1024 * 8];
  const int tid = threadIdx.x;
  const int wave = tid >> 6, lane = tid & 63;
  const int row0 = blockIdx.y * 128, col0 = blockIdx.x * 128;
  const int m_in = lane & 15, quad = lane >> 4;
  const int wm = (wave >> 1) * 64, wn = (wave & 1) * 64;
  f32x4 acc[4][4] = {};
  for (int kt = 0; kt < K; kt += 64) {
    for (int i = 0; i < 4; ++i) {
      int s = (i * 4 + wave) * 64 + lane;
      int r = s >> 3, cs = s & 7, cd = cs ^ (r & 7);
      async_cp16(A + ((size_t)(row0 + r) * K + kt + cd * 8), &As[s * 8]);
      async_cp16(B + ((size_t)(col0 + r) * K + kt + cd * 8), &Bs[s * 8]);
    }
    __syncthreads();
    for (int kk = 0; kk < 2; ++kk) {
      s16x8 af[4], bfr[4];
      int c = kk * 4 + quad;
      for (int i = 0; i < 4; ++i) {
        int ra = wm + i * 16 + m_in;
        af[i] = *(const s16x8*)&As[(ra * 8 + (c ^ (ra & 7))) * 8];
        int rb = wn + i * 16 + m_in;
        bfr[i] = *(const s16x8*)&Bs[(rb * 8 + (c ^ (rb & 7))) * 8];
      }
      for (int i = 0; i < 4; ++i)
        for (int j = 0; j < 4; ++j)
          acc[i][j] = MFMA16(af[i], bfr[j], acc[i][j], 0, 0, 0);
    }
    __syncthreads();
  }
  for (int j = 0; j < 4; ++j) {
    int n = col0 + wn + j * 16 + m_in;
    float bs = bias0[n] + (bias1 ? bias1[n] : 0.f);
    for (int i = 0; i < 4; ++i) {
      int mrow = row0 + wm + i * 16 + quad * 4;
      f32x4 a = acc[i][j];
      for (int p = 0; p < 4; ++p)
        out[(size_t)(mrow + p) * ldo + n] = a[p] + bs;
    }
  }
}

// ---------------------------------------------------------------------------
// Fused recurrence + logits GEMM.
//   role < 16  : recurrence block S. 8 waves; wave w owns units S*32+w*4..+4
//                for ALL 4 gates (gate-major B-row mapping), W frags in VGPRs.
//   role >= 16 : persistent worker; tiles tau = (role-16) + 240k over
//                4000 = 16(ty) x 250(tx); tile (ty,tx) needs steps <= ty*8+7.
// flags[S*16]: per-block sum barrier; each wave += 1 per step (8*step total).
__global__ __launch_bounds__(512, 1) void fused_rec_logits(
    const float* __restrict__ G0,    // [2048][2048] fp32, rows t-major
    const short* __restrict__ Whh,   // [2048][512] bf16
    const float* __restrict__ h0, const float* __restrict__ c0,
    short* __restrict__ Hs,          // [2048][512] bf16, rows t-major
    const short* __restrict__ Wout,  // [32000][512] bf16
    const float* __restrict__ bout,
    int* flags,
    float* __restrict__ out,         // logits, row b*T+t
    float* __restrict__ hcf,         // hf[B*H] then cf[B*H]
    int block_base)
{
  __shared__ char smem[86016];       // 84KB -> exactly 1 block/CU (residency)
  const int role = blockIdx.x + block_base;
  const int tid = threadIdx.x, wave = tid >> 6, lane = tid & 63;

  if (role < 16) {
    // ------------------------- recurrence -------------------------
    const int S = role;
    const int nin = lane & 15, quad = lane >> 4;     // writer: col,batchgrp / reader: batch,unit-j
    const int g = nin >> 2, j = nin & 3;             // gate-major B-row mapping
    // W fragments resident in VGPRs: B-row nin -> W_hh row g*512 + S*32 + w*4 + j
    s16x8 wf[16];
    {
      const short* wrow = Whh + ((size_t)(g * 512 + S * 32 + wave * 4 + j)) * 512;
#pragma unroll
      for (int ks = 0; ks < 16; ++ks)
        wf[ks] = *(const s16x8*)&wrow[ks * 32 + quad * 8];
    }
    const int goff = S * 32 + wave * 4 + quad;       // this lane's unit (reader view)
    float c_reg = c0[nin * 512 + goff];
    float* gw = (float*)smem + wave * 320;           // per-wave 16 x 20 fp32 scratch
    // G0 prefetch for tt=0 (row = 0*16 + nin)
    float gx0 = G0[(size_t)nin * 2048 + goff];
    float gx1 = G0[(size_t)nin * 2048 + 512 + goff];
    float gx2 = G0[(size_t)nin * 2048 + 1024 + goff];
    float gx3 = G0[(size_t)nin * 2048 + 1536 + goff];
    int* myflag = &flags[S * 16];

    for (int tt = 0; tt < T_; ++tt) {
      if (tt > 0) {
        const int target = 8 * tt;                   // all blocks: 8 waves x tt steps
        while (true) {
          int f = 0x7fffffff;
          if (lane < 16)
            f = __hip_atomic_load(&flags[lane * 16], __ATOMIC_RELAXED, __HIP_MEMORY_SCOPE_AGENT);
          if (__ballot(f >= target) == ~0ull) break;
          __builtin_amdgcn_s_sleep(1);
        }
        asm volatile("" ::: "memory");               // no load hoisting above spin
      }
      // MFMA: 16 batches x 16 (gate,unit) rows over K=512, two acc chains
      f32x4 a0 = {}, a1 = {};
      if (tt == 0) {
#pragma unroll
        for (int ks = 0; ks < 16; ++ks) {
          const float* hp = h0 + nin * 512 + ks * 32 + quad * 8;
          float4 v0 = *(const float4*)hp, v1 = *(const float4*)(hp + 4);
          s16x8 af;
          af[0] = f2bf(v0.x); af[1] = f2bf(v0.y); af[2] = f2bf(v0.z); af[3] = f2bf(v0.w);
          af[4] = f2bf(v1.x); af[5] = f2bf(v1.y); af[6] = f2bf(v1.z); af[7] = f2bf(v1.w);
          if (ks < 8) a0 = MFMA16(af, wf[ks], a0, 0, 0, 0);
          else        a1 = MFMA16(af, wf[ks], a1, 0, 0, 0);
        }
      } else {
        const short* hrow = Hs + ((size_t)(tt - 1) * 16 + nin) * 512 + quad * 8;
#pragma unroll
        for (int ks = 0; ks < 16; ++ks) {
          s16x8 af = load_h16(hrow + ks * 32);
          if (ks < 8) a0 = MFMA16(af, wf[ks], a0, 0, 0, 0);
          else        a1 = MFMA16(af, wf[ks], a1, 0, 0, 0);
        }
      }
      f32x4 acc = a0 + a1;
      // in-wave gate exchange (no barrier; compiler orders ds ops per-wave)
      *(f32x4*)&gw[nin * 20 + quad * 4] = acc;       // [col=nin][batch]
      float pi = gw[(0 * 4 + quad) * 20 + nin];
      float pf = gw[(1 * 4 + quad) * 20 + nin];
      float pg = gw[(2 * 4 + quad) * 20 + nin];
      float po = gw[(3 * 4 + quad) * 20 + nin];
      float xi = gx0 + pi, xf = gx1 + pf, xg = gx2 + pg, xo = gx3 + po;
      float si = 1.f / (1.f + __expf(-xi));
      float sf = 1.f / (1.f + __expf(-xf));
      float so = 1.f / (1.f + __expf(-xo));
      c_reg = sf * c_reg + si * tanhf(xg);
      float hn = so * tanhf(c_reg);
      if (tt < T_ - 1) {                             // prefetch next G0 row
        const float* gp = G0 + ((size_t)(tt + 1) * 16 + nin) * 2048 + goff;
        gx0 = gp[0]; gx1 = gp[512]; gx2 = gp[1024]; gx3 = gp[1536];
      }
      // pack this wave's 4 units for batch nin, store 8B device-coherent
      int v0 = (int)(unsigned short)f2bf(hn);
      int v1 = __shfl(v0, (lane & 15) + 16);
      int v2 = __shfl(v0, (lane & 15) + 32);
      int v3 = __shfl(v0, (lane & 15) + 48);
      if (lane < 16) {
        unsigned long long pk = (unsigned long long)(unsigned)v0
                              | ((unsigned long long)(unsigned)v1 << 16)
                              | ((unsigned long long)(unsigned)v2 << 32)
                              | ((unsigned long long)(unsigned)v3 << 48);
        __hip_atomic_store(
            (unsigned long long*)&Hs[((size_t)tt * 16 + nin) * 512 + S * 32 + wave * 4],
            pk, __ATOMIC_RELAXED, __HIP_MEMORY_SCOPE_AGENT);
      }
      if (tt == T_ - 1) {
        hcf[nin * 512 + goff] = hn;
        hcf[B_ * H_ + nin * 512 + goff] = c_reg;
      }
      asm volatile("s_waitcnt vmcnt(0)" ::: "memory"); // stores acked at IF
      if (lane == 0)
        __hip_atomic_fetch_add(myflag, 1, __ATOMIC_RELAXED, __HIP_MEMORY_SCOPE_AGENT);
    }
  } else {
    // ------------------------- logits workers -------------------------
    const int w = role - 16;                         // 0..239
    short* As = (short*)smem;
    short* Bs = (short*)(smem + 16384);
    const int m_in = lane & 15, quad = lane >> 4;
    const int wm = (wave >> 1) * 32, wn = (wave & 1) * 64;   // 8 waves: 4x2
    for (int tile = w; tile < 4000; tile += 240) {
      int ty = tile / 250, tx = tile - ty * 250;
      if (tid == 0) {
        const int target = 64 * (ty + 1);            // 8 waves * 8*(ty+1) steps
        for (int s = 0; s < 16; ++s)
          while (__hip_atomic_load(&flags[s * 16], __ATOMIC_RELAXED, __HIP_MEMORY_SCOPE_AGENT) < target)
            __builtin_amdgcn_s_sleep(2);
        __threadfence();                             // acquire: drop stale L1/L2
      }
      __syncthreads();
      f32x4 acc[2][4] = {};
      const short* Arows = Hs + (size_t)ty * 128 * 512;
      const short* Brows = Wout + (size_t)tx * 128 * 512;
      for (int kt = 0; kt < 512; kt += 64) {
#pragma unroll
        for (int i = 0; i < 2; ++i) {
          int s = i * 512 + tid;
          int r = s >> 3, cs = s & 7, cd = cs ^ (r & 7);
          async_cp16(Arows + ((size_t)r * 512 + kt + cd * 8), &As[s * 8]);
          async_cp16(Brows + ((size_t)r * 512 + kt + cd * 8), &Bs[s * 8]);
        }
        __syncthreads();
#pragma unroll
        for (int kk = 0; kk < 2; ++kk) {
          int c = kk * 4 + quad;
          s16x8 af[2], bfr[4];
#pragma unroll
          for (int i = 0; i < 2; ++i) {
            int ra = wm + i * 16 + m_in;
            af[i] = *(const s16x8*)&As[(ra * 8 + (c ^ (ra & 7))) * 8];
          }
#pragma unroll
          for (int jn = 0; jn < 4; ++jn) {
            int rb = wn + jn * 16 + m_in;
            bfr[jn] = *(const s16x8*)&Bs[(rb * 8 + (c ^ (rb & 7))) * 8];
          }
#pragma unroll
          for (int i = 0; i < 2; ++i)
#pragma unroll
            for (int jn = 0; jn < 4; ++jn)
              acc[i][jn] = MFMA16(af[i], bfr[jn], acc[i][jn], 0, 0, 0);
        }
        __syncthreads();
      }
#pragma unroll
      for (int jn = 0; jn < 4; ++jn) {
        int n = tx * 128 + wn + jn * 16 + m_in;
        float bs = bout[n];
#pragma unroll
        for (int i = 0; i < 2; ++i) {
          int mloc = wm + i * 16 + quad * 4;
          f32x4 a = acc[i][jn];
#pragma unroll
          for (int p = 0; p < 4; ++p) {
            int ml = mloc + p;
            int t = ty * 8 + (ml >> 4), b = ml & 15;
            out[((size_t)b * T_ + t) * (size_t)V_ + n] = a[p] + bs;
          }
        }
      }
    }
  }
}

// ---------------------------------------------------------------------------
extern "C" void kernel_launch(void* const* d_in, const int* in_sizes, int n_in,
                              void* d_out, int out_size, void* d_ws, size_t ws_size,
                              hipStream_t stream) {
  (void)in_sizes; (void)n_in; (void)out_size;
  const float* h0   = (const float*)d_in[1];
  const float* c0   = (const float*)d_in[2];
  const int*   tgt  = (const int*)d_in[3];
  const float* emb  = (const float*)d_in[4];
  const float* Wih  = (const float*)d_in[5];
  const float* Whh  = (const float*)d_in[6];
  const float* bih  = (const float*)d_in[7];
  const float* bhh  = (const float*)d_in[8];
  const float* Wout = (const float*)d_in[9];
  const float* bout = (const float*)d_in[10];
  float* out = (float*)d_out;

  char* ws = (char*)d_ws;
  short* wsWout = (short*)(ws);                 // 32,768,000 B
  short* wsWih  = (short*)(ws + 32768000);      //  2,097,152 B
  short* wsWhh  = (short*)(ws + 34865152);      //  2,097,152 B
  short* wsX    = (short*)(ws + 36962304);      //  2,097,152 B
  short* wsHs   = (short*)(ws + 39059456);      //  2,097,152 B
  int*   flags  = (int*)  (ws + 41156608);      //      4,096 B
  const size_t NEED = 41160704ull + 16777216ull; // + G0 fp32
  const bool fused = (ws_size >= NEED);
  float* G0 = fused ? (float*)(ws + 41160704) : out;  // fallback: d_out scratch

  cvt_bf16<<<16000, 256, 0, stream>>>(Wout, wsWout, 4096000);
  cvt_bf16<<<1024, 256, 0, stream>>>(Wih, wsWih, 262144);
  cvt_bf16<<<1024, 256, 0, stream>>>(Whh, wsWhh, 262144);
  gather_embed<<<2048, 128, 0, stream>>>(emb, tgt, wsX, flags);
  gemm_bt<<<dim3(16, 16), 256, 0, stream>>>(wsX, wsWih, bih, bhh, G0, 2048, 2048, 512, 2048);
  float* hcf = out + (size_t)B_ * T_ * V_;
  if (fused) {
    // 256 blocks = 256 CUs, 1/CU (84KB LDS) -> all co-resident, no deadlock.
    fused_rec_logits<<<256, 512, 0, stream>>>(G0, wsWhh, h0, c0, wsHs, wsWout,
                                              bout, flags, out, hcf, 0);
  } else {
    // sequential fallback: recurrence first (G0 in d_out scratch), then workers
    fused_rec_logits<<<16, 512, 0, stream>>>(G0, wsWhh, h0, c0, wsHs, wsWout,
                                             bout, flags, out, hcf, 0);
    fused_rec_logits<<<240, 512, 0, stream>>>(G0, wsWhh, h0, c0, wsHs, wsWout,
                                              bout, flags, out, hcf, 16);
  }
}

// Round 2
// 1886.894 us; speedup vs baseline: 1.0089x; 1.0089x over previous
//
#include <hip/hip_runtime.h>
#include <hip/hip_bf16.h>
#include <cstdint>

// ---------------------------------------------------------------------------
// Decoder LSTM (teacher-forced), MI355X.
//   1. cvt_bf16: W_out, W_ih, W_hh fp32 -> bf16 (ws)
//   2. gather_embed: X[t*16+b] = bf16(relu(emb[tok])) (t-major), zero flags
//   3. gemm_bt: G0 = X @ W_ih^T + b_ih + b_hh  (fp32, t-major rows)
//   4. lstm_rec: 16 blocks x 512 thr. W_hh slice in REGISTERS, h exchange via
//      relaxed agent-scope (write-through to IF) atomics, per-block sum-flag,
//      in-wave LDS gate exchange -> NO __syncthreads / threadfence in the
//      128-step loop. G0 prefetch after flag-add (overlaps next spin).
//   5. gemm_bt (tmajor epilogue): logits = Hs @ W_out^T + b_out -> d_out
// Sequential phases (the fused worker overlap regressed 947->1903 us from
// flag-spin contention + per-tile buffer_inv; measured MfmaUtil 1.8%).
// ---------------------------------------------------------------------------

#define V_ 32000
#define H_ 512
#define B_ 16
#define T_ 128

typedef __attribute__((ext_vector_type(8))) short s16x8;
typedef __attribute__((ext_vector_type(4))) float f32x4;

typedef unsigned int __attribute__((address_space(1))) as1_u32;
typedef unsigned int __attribute__((address_space(3))) as3_u32;

#define MFMA16 __builtin_amdgcn_mfma_f32_16x16x32_bf16

__device__ __forceinline__ void async_cp16(const void* g, void* l) {
  __builtin_amdgcn_global_load_lds((const as1_u32*)g, (as3_u32*)l, 16, 0, 0);
}

__device__ __forceinline__ short f2bf(float f) {
  union { float f; unsigned u; } v; v.f = f;
  unsigned r = v.u + 0x7fffu + ((v.u >> 16) & 1u);   // RNE, inputs finite
  return (short)(r >> 16);
}

// 16B coherent load: two relaxed agent-scope atomic 64-bit loads (sc0/sc1,
// bypass stale L1/L2, served at the IF coherence point).
__device__ __forceinline__ s16x8 load_h16(const short* p) {
  unsigned long long* q = (unsigned long long*)(void*)p;
  unsigned long long lo = __hip_atomic_load(q, __ATOMIC_RELAXED, __HIP_MEMORY_SCOPE_AGENT);
  unsigned long long hi = __hip_atomic_load(q + 1, __ATOMIC_RELAXED, __HIP_MEMORY_SCOPE_AGENT);
  union { unsigned long long u[2]; s16x8 v; } r;
  r.u[0] = lo; r.u[1] = hi;
  return r.v;
}

// ---------------------------------------------------------------------------
__global__ void cvt_bf16(const float* __restrict__ in, short* __restrict__ out, int n4) {
  int i = blockIdx.x * blockDim.x + threadIdx.x;
  if (i >= n4) return;
  float4 v = ((const float4*)in)[i];
  short4 o;
  o.x = f2bf(v.x); o.y = f2bf(v.y); o.z = f2bf(v.z); o.w = f2bf(v.w);
  ((short4*)out)[i] = o;
}

// grid 2048 blocks (one per (b,t)), 128 threads. X stored T-MAJOR: row t*16+b.
__global__ void gather_embed(const float* __restrict__ emb, const int* __restrict__ tgt,
                             short* __restrict__ X, int* __restrict__ flags) {
  int m = blockIdx.x;
  int b = m >> 7, t = m & 127;
  int tok = (t == 0) ? 1 : tgt[b * T_ + t - 1];       // BOS = 1
  int k = threadIdx.x * 4;
  float4 v = *(const float4*)&emb[(size_t)tok * H_ + k];
  short4 o;
  o.x = f2bf(fmaxf(v.x, 0.f)); o.y = f2bf(fmaxf(v.y, 0.f));
  o.z = f2bf(fmaxf(v.z, 0.f)); o.w = f2bf(fmaxf(v.w, 0.f));
  *(short4*)&X[((size_t)t * 16 + b) * H_ + k] = o;
  if (m == 0) {                                       // zero 256 flag ints
    flags[threadIdx.x] = 0;
    flags[128 + threadIdx.x] = 0;
  }
}

// ---------------------------------------------------------------------------
// C = A(MxK bf16) @ B(NxK bf16)^T + bias ; 128x128 tile, BK=64, 4 waves,
// XOR-swizzled LDS chunks -> conflict-free ds_read_b128.
// tmajor: A rows are t*16+b, output rows must be b*T+t (logits GEMM).
__global__ __launch_bounds__(256, 2) void gemm_bt(
    const short* __restrict__ A, const short* __restrict__ B,
    const float* __restrict__ bias0, const float* __restrict__ bias1,
    float* __restrict__ out, int M, int N, int K, int ldo, int tmajor)
{
  __shared__ short As[1024 * 8];
  __shared__ short Bs[1024 * 8];
  const int tid = threadIdx.x;
  const int wave = tid >> 6, lane = tid & 63;
  const int row0 = blockIdx.y * 128, col0 = blockIdx.x * 128;
  const int m_in = lane & 15, quad = lane >> 4;
  const int wm = (wave >> 1) * 64, wn = (wave & 1) * 64;
  f32x4 acc[4][4] = {};
  for (int kt = 0; kt < K; kt += 64) {
    for (int i = 0; i < 4; ++i) {
      int s = (i * 4 + wave) * 64 + lane;
      int r = s >> 3, cs = s & 7, cd = cs ^ (r & 7);
      async_cp16(A + ((size_t)(row0 + r) * K + kt + cd * 8), &As[s * 8]);
      async_cp16(B + ((size_t)(col0 + r) * K + kt + cd * 8), &Bs[s * 8]);
    }
    __syncthreads();
    for (int kk = 0; kk < 2; ++kk) {
      s16x8 af[4], bfr[4];
      int c = kk * 4 + quad;
      for (int i = 0; i < 4; ++i) {
        int ra = wm + i * 16 + m_in;
        af[i] = *(const s16x8*)&As[(ra * 8 + (c ^ (ra & 7))) * 8];
        int rb = wn + i * 16 + m_in;
        bfr[i] = *(const s16x8*)&Bs[(rb * 8 + (c ^ (rb & 7))) * 8];
      }
      for (int i = 0; i < 4; ++i)
        for (int j = 0; j < 4; ++j)
          acc[i][j] = MFMA16(af[i], bfr[j], acc[i][j], 0, 0, 0);
    }
    __syncthreads();
  }
  for (int j = 0; j < 4; ++j) {
    int n = col0 + wn + j * 16 + m_in;
    float bs = bias0[n] + (bias1 ? bias1[n] : 0.f);
    for (int i = 0; i < 4; ++i) {
      int mrow = row0 + wm + i * 16 + quad * 4;      // D: col=lane&15, row=quad*4+reg
      f32x4 a = acc[i][j];
      for (int p = 0; p < 4; ++p) {
        int mr = mrow + p;
        int orow = tmajor ? ((mr & 15) * T_ + (mr >> 4)) : mr;
        out[(size_t)orow * ldo + n] = a[p] + bs;
      }
    }
  }
}

// ---------------------------------------------------------------------------
// Recurrence: 16 blocks x 512 threads (8 waves). Block S owns hidden slice
// [S*32, S*32+32); wave w owns units S*32+w*4..+4 for ALL 4 gates.
// W_hh fragments resident in VGPRs (64/lane). Per step:
//   spin(flags) -> 16 IF-coherent h loads -> 2 MFMA chains -> in-wave LDS
//   gate exchange -> fp32 gate math -> pack h -> 8B IF store -> vmcnt(0) ->
//   flag += 1 (per wave) -> G0 prefetch for t+1 (overlaps next spin).
// flag[s] >= 8*t  <=>  every wave of block s completed steps 0..t-1.
__global__ __launch_bounds__(512, 1) void lstm_rec(
    const float* __restrict__ G0,    // [2048][2048] fp32, rows t-major
    const short* __restrict__ Whh,   // [2048][512] bf16
    const float* __restrict__ h0, const float* __restrict__ c0,
    short* __restrict__ Hs,          // [2048][512] bf16, rows t-major
    int* flags,
    float* __restrict__ hcf)         // hf[B*H] then cf[B*H]
{
  __shared__ float gw_s[8 * 320];    // per-wave 16x20 fp32 scratch
  const int S = blockIdx.x;
  const int tid = threadIdx.x, wave = tid >> 6, lane = tid & 63;
  const int nin = lane & 15, quad = lane >> 4;
  const int g = nin >> 2, j = nin & 3;               // gate-major B-row mapping

  // W fragments: B-row nin -> W_hh row g*512 + S*32 + wave*4 + j
  s16x8 wf[16];
  {
    const short* wrow = Whh + ((size_t)(g * 512 + S * 32 + wave * 4 + j)) * 512;
#pragma unroll
    for (int ks = 0; ks < 16; ++ks)
      wf[ks] = *(const s16x8*)&wrow[ks * 32 + quad * 8];
  }
  const int goff = S * 32 + wave * 4 + quad;         // this lane's unit (reader view)
  float c_reg = c0[nin * 512 + goff];
  float* gw = gw_s + wave * 320;
  // G0 prefetch for tt=0 (row = 0*16 + nin)
  float gx0 = G0[(size_t)nin * 2048 + goff];
  float gx1 = G0[(size_t)nin * 2048 + 512 + goff];
  float gx2 = G0[(size_t)nin * 2048 + 1024 + goff];
  float gx3 = G0[(size_t)nin * 2048 + 1536 + goff];
  int* myflag = &flags[S * 16];

  for (int tt = 0; tt < T_; ++tt) {
    if (tt > 0) {
      const int target = 8 * tt;
      while (true) {
        int f = 0x7fffffff;
        if (lane < 16)
          f = __hip_atomic_load(&flags[lane * 16], __ATOMIC_RELAXED, __HIP_MEMORY_SCOPE_AGENT);
        if (__ballot(f >= target) == ~0ull) break;
        __builtin_amdgcn_s_sleep(1);
      }
      asm volatile("" ::: "memory");                 // no load hoisting above spin
    }
    // MFMA: 16 batches x 16 (gate,unit) rows over K=512, two acc chains
    f32x4 a0 = {}, a1 = {};
    if (tt == 0) {
#pragma unroll
      for (int ks = 0; ks < 16; ++ks) {
        const float* hp = h0 + nin * 512 + ks * 32 + quad * 8;
        float4 v0 = *(const float4*)hp, v1 = *(const float4*)(hp + 4);
        s16x8 af;
        af[0] = f2bf(v0.x); af[1] = f2bf(v0.y); af[2] = f2bf(v0.z); af[3] = f2bf(v0.w);
        af[4] = f2bf(v1.x); af[5] = f2bf(v1.y); af[6] = f2bf(v1.z); af[7] = f2bf(v1.w);
        if (ks < 8) a0 = MFMA16(af, wf[ks], a0, 0, 0, 0);
        else        a1 = MFMA16(af, wf[ks], a1, 0, 0, 0);
      }
    } else {
      const short* hrow = Hs + ((size_t)(tt - 1) * 16 + nin) * 512 + quad * 8;
#pragma unroll
      for (int ks = 0; ks < 16; ++ks) {
        s16x8 af = load_h16(hrow + ks * 32);
        if (ks < 8) a0 = MFMA16(af, wf[ks], a0, 0, 0, 0);
        else        a1 = MFMA16(af, wf[ks], a1, 0, 0, 0);
      }
    }
    f32x4 acc = a0 + a1;
    // in-wave gate exchange (no barrier; lgkmcnt orders ds ops per-wave)
    *(f32x4*)&gw[nin * 20 + quad * 4] = acc;         // [col=(g,j)][batch]
    float pi = gw[(0 * 4 + quad) * 20 + nin];
    float pf = gw[(1 * 4 + quad) * 20 + nin];
    float pg = gw[(2 * 4 + quad) * 20 + nin];
    float po = gw[(3 * 4 + quad) * 20 + nin];
    float xi = gx0 + pi, xf = gx1 + pf, xg = gx2 + pg, xo = gx3 + po;
    float si = 1.f / (1.f + __expf(-xi));
    float sf = 1.f / (1.f + __expf(-xf));
    float so = 1.f / (1.f + __expf(-xo));
    c_reg = sf * c_reg + si * tanhf(xg);
    float hn = so * tanhf(c_reg);
    // pack this wave's 4 units for batch nin, store 8B device-coherent
    int v0 = (int)(unsigned short)f2bf(hn);
    int v1 = __shfl(v0, (lane & 15) + 16);
    int v2 = __shfl(v0, (lane & 15) + 32);
    int v3 = __shfl(v0, (lane & 15) + 48);
    if (lane < 16) {
      unsigned long long pk = (unsigned long long)(unsigned)v0
                            | ((unsigned long long)(unsigned)v1 << 16)
                            | ((unsigned long long)(unsigned)v2 << 32)
                            | ((unsigned long long)(unsigned)v3 << 48);
      __hip_atomic_store(
          (unsigned long long*)&Hs[((size_t)tt * 16 + nin) * 512 + S * 32 + wave * 4],
          pk, __ATOMIC_RELAXED, __HIP_MEMORY_SCOPE_AGENT);
    }
    if (tt == T_ - 1) {
      hcf[nin * 512 + goff] = hn;
      hcf[B_ * H_ + nin * 512 + goff] = c_reg;
    }
    asm volatile("s_waitcnt vmcnt(0)" ::: "memory"); // Hs store acked at IF
    if (lane == 0)
      __hip_atomic_fetch_add(myflag, 1, __ATOMIC_RELAXED, __HIP_MEMORY_SCOPE_AGENT);
    if (tt < T_ - 1) {                               // prefetch next G0 row;
      const float* gp = G0 + ((size_t)(tt + 1) * 16 + nin) * 2048 + goff;
      gx0 = gp[0]; gx1 = gp[512]; gx2 = gp[1024]; gx3 = gp[1536];
    }                                                // latency hides under spin
  }
}

// ---------------------------------------------------------------------------
extern "C" void kernel_launch(void* const* d_in, const int* in_sizes, int n_in,
                              void* d_out, int out_size, void* d_ws, size_t ws_size,
                              hipStream_t stream) {
  (void)in_sizes; (void)n_in; (void)out_size;
  const float* h0   = (const float*)d_in[1];
  const float* c0   = (const float*)d_in[2];
  const int*   tgt  = (const int*)d_in[3];
  const float* emb  = (const float*)d_in[4];
  const float* Wih  = (const float*)d_in[5];
  const float* Whh  = (const float*)d_in[6];
  const float* bih  = (const float*)d_in[7];
  const float* bhh  = (const float*)d_in[8];
  const float* Wout = (const float*)d_in[9];
  const float* bout = (const float*)d_in[10];
  float* out = (float*)d_out;

  char* ws = (char*)d_ws;
  short* wsWout = (short*)(ws);                 // 32,768,000 B
  short* wsWih  = (short*)(ws + 32768000);      //  2,097,152 B
  short* wsWhh  = (short*)(ws + 34865152);      //  2,097,152 B
  short* wsX    = (short*)(ws + 36962304);      //  2,097,152 B
  short* wsHs   = (short*)(ws + 39059456);      //  2,097,152 B
  int*   flags  = (int*)  (ws + 41156608);      //      4,096 B
  const size_t NEED = 41160704ull + 16777216ull;
  // G0 in ws if it fits; else d_out scratch (safe: lstm_rec finishes reading
  // G0 before the logits gemm starts overwriting out — same stream).
  float* G0 = (ws_size >= NEED) ? (float*)(ws + 41160704) : out;

  cvt_bf16<<<16000, 256, 0, stream>>>(Wout, wsWout, 4096000);
  cvt_bf16<<<1024, 256, 0, stream>>>(Wih, wsWih, 262144);
  cvt_bf16<<<1024, 256, 0, stream>>>(Whh, wsWhh, 262144);
  gather_embed<<<2048, 128, 0, stream>>>(emb, tgt, wsX, flags);
  gemm_bt<<<dim3(16, 16), 256, 0, stream>>>(wsX, wsWih, bih, bhh, G0,
                                            2048, 2048, 512, 2048, 0);
  float* hcf = out + (size_t)B_ * T_ * V_;
  lstm_rec<<<16, 512, 0, stream>>>(G0, wsWhh, h0, c0, wsHs, flags, hcf);
  gemm_bt<<<dim3(250, 16), 256, 0, stream>>>(wsHs, wsWout, bout, nullptr, out,
                                             2048, 32000, 512, 32000, 1);
}